// Round 9
// baseline (439.538 us; speedup 1.0000x reference)
//
#include <hip/hip_runtime.h>
#include <hip/hip_bf16.h>

// ---------- types & helpers ----------
typedef __bf16 bf16x8 __attribute__((ext_vector_type(8)));
typedef float f32x4 __attribute__((ext_vector_type(4)));

__device__ __forceinline__ float bf2f(unsigned short u) {
  union { unsigned int i; float f; } v; v.i = ((unsigned int)u) << 16; return v.f;
}
__device__ __forceinline__ unsigned short f2bf(float f) {
  union { unsigned int i; float f; } v; v.f = f;
  unsigned int i = v.i;
  return (unsigned short)((i + 0x7FFFu + ((i >> 16) & 1u)) >> 16);  // RNE
}

// async global->LDS, 16B per lane; LDS dest = wave-uniform base + lane*16
typedef const __attribute__((address_space(1))) unsigned int* gas_ptr;
typedef __attribute__((address_space(3))) unsigned int* las_ptr;
__device__ __forceinline__ void gload_lds16(const unsigned short* g, unsigned short* l) {
  __builtin_amdgcn_global_load_lds((gas_ptr)(const void*)g, (las_ptr)(void*)l, 16, 0, 0);
}

// ---------- fused prologue: detect + hidden cvt + both weight transposes ----------
// Every block self-detects dtype (deterministic 2048-sample probe, L2-cached).
// blocks [0,2048):        hidden fp32->bf16 cvt (no-op when input is bf16)
// blocks [2048,14336):    W_qkv  [2048,6144] -> Wt_qkv  [6144,2048]
// blocks [14336,18432):   W_proj [2048,2048] -> Wt_proj [2048,2048]
__global__ __launch_bounds__(256) void prologue_k(const void* __restrict__ hidden,
                                                  const void* __restrict__ w_qkv,
                                                  const void* __restrict__ w_proj,
                                                  unsigned short* __restrict__ hidden_bf,
                                                  unsigned short* __restrict__ Wt_qkv,
                                                  unsigned short* __restrict__ Wt_proj,
                                                  int* __restrict__ flag) {
  __shared__ unsigned short tile[32][33];
  __shared__ int s4[4];
  const int t = threadIdx.x;
  // --- local dtype detect: sample 2048 even-indexed shorts of hidden ---
  {
    const unsigned short* h = (const unsigned short*)hidden;
    int cnt = 0;
    for (int i = t; i < 2048; i += 256) {
      unsigned short u = h[2 * i];
      int e = (u >> 7) & 0xFF;
      cnt += ((e >= 96 && e <= 140) || u == 0) ? 1 : 0;
    }
#pragma unroll
    for (int off = 1; off < 64; off <<= 1) cnt += __shfl_xor(cnt, off, 64);
    if ((t & 63) == 0) s4[t >> 6] = cnt;
  }
  __syncthreads();
  const int f = (s4[0] + s4[1] + s4[2] + s4[3]) >= 1800;  // bf16 => ~2048; fp32 => ~370
  if (blockIdx.x == 0 && t == 0) *flag = f;

  int bid = blockIdx.x;
  if (bid < 2048) {                 // hidden cvt (fp32 path only)
    if (f) return;
    const float* src = (const float*)hidden;
    int base = bid * 4096;
#pragma unroll
    for (int k = 0; k < 16; k++) hidden_bf[base + t + 256 * k] = f2bf(src[base + t + 256 * k]);
    return;
  }
  const void* src; unsigned short* dst; int C, cx, cy;
  if (bid < 14336) { bid -= 2048;  src = w_qkv;  dst = Wt_qkv;  C = 6144; cx = bid % 192; cy = bid / 192; }
  else             { bid -= 14336; src = w_proj; dst = Wt_proj; C = 2048; cx = bid % 64;  cy = bid / 64;  }
  const int x = t & 31, y = t >> 5;
  const int r0 = cy * 32, c0 = cx * 32;
#pragma unroll
  for (int i = 0; i < 4; i++) {
    size_t idx = (size_t)(r0 + y + 8 * i) * C + c0 + x;
    tile[y + 8 * i][x] = f ? ((const unsigned short*)src)[idx]
                           : f2bf(((const float*)src)[idx]);
  }
  __syncthreads();
#pragma unroll
  for (int i = 0; i < 4; i++)
    dst[(size_t)(c0 + y + 8 * i) * 2048 + r0 + x] = tile[x][y + 8 * i];
}

// ---------- GEMM 128x128 tile: global_load_lds + XOR-swizzled LDS (854 TF) ----------
// v_fuse: blocks with n0>=4096 write their tile TRANSPOSED to Vt (V-head layout
// [(b*16+h)*128+d][key]) via an LDS round-trip, skipping the QKV V-region write.
__global__ __launch_bounds__(256) void gemm_bias_k(const unsigned short* __restrict__ A_bf,
                                                   const unsigned short* __restrict__ A_cvt,
                                                   const unsigned short* __restrict__ Bt,
                                                   const void* __restrict__ bias,
                                                   void* __restrict__ Cout,
                                                   unsigned short* __restrict__ Vt,
                                                   int M, int N, int K,
                                                   const int* __restrict__ flag,
                                                   int final_out, int v_fuse) {
  __shared__ __attribute__((aligned(16))) unsigned short smem[2][128][64];
#define As smem[0]
#define Bs smem[1]
  const int f = *flag;
  const unsigned short* A = f ? A_bf : A_cvt;
  const int t = threadIdx.x;
  const int wave = t >> 6, lane = t & 63;
  const int col = lane & 15, quad = lane >> 4;
  const int wm = wave >> 1, wn = wave & 1;
  const int m0 = blockIdx.y * 128, n0 = blockIdx.x * 128;
  const int srow = lane >> 3;                       // row within 8-row segment
  const int schunk = ((lane & 7) ^ srow) * 8;       // swizzled source chunk (shorts)
  const int rsw = col & 7;                          // read-side swizzle key

  const f32x4 fzero = {0.f, 0.f, 0.f, 0.f};
  f32x4 acc[4][4];
#pragma unroll
  for (int i = 0; i < 4; i++)
#pragma unroll
    for (int j = 0; j < 4; j++) acc[i][j] = fzero;

  for (int k0 = 0; k0 < K; k0 += 64) {
    __syncthreads();
#pragma unroll
    for (int c = 0; c < 4; c++) {
      int seg = wave * 4 + c;          // 16 segments of 8 rows
      int row = seg * 8 + srow;
      gload_lds16(&A [(size_t)(m0 + row) * K + k0 + schunk], &As[seg * 8][0]);
      gload_lds16(&Bt[(size_t)(n0 + row) * K + k0 + schunk], &Bs[seg * 8][0]);
    }
    __syncthreads();  // drains vmcnt
#pragma unroll
    for (int ks = 0; ks < 2; ks++) {
      bf16x8 af[4], bfr[4];
#pragma unroll
      for (int i = 0; i < 4; i++)
        af[i] = *(const bf16x8*)&As[wm * 64 + i * 16 + col][(((ks << 2) | quad) ^ rsw) * 8];
#pragma unroll
      for (int j = 0; j < 4; j++)
        bfr[j] = *(const bf16x8*)&Bs[wn * 64 + j * 16 + col][(((ks << 2) | quad) ^ rsw) * 8];
#pragma unroll
      for (int i = 0; i < 4; i++)
#pragma unroll
        for (int j = 0; j < 4; j++)
          acc[i][j] = __builtin_amdgcn_mfma_f32_16x16x32_bf16(af[i], bfr[j], acc[i][j], 0, 0, 0);
    }
  }

  if (v_fuse && n0 >= 4096) {
    // ---- V epilogue: transpose tile to Vt[(b*16+h)*128+d][key] ----
    const int bb = m0 >> 11, hh = (n0 - 4096) >> 7, s0k = m0 & 2047;
    unsigned short* Tr = &smem[0][0][0];  // [64][130] shorts (16.6 KB, fits 32 KB)
#pragma unroll
    for (int half = 0; half < 2; half++) {
      __syncthreads();  // As/Bs (or previous half) dead
      if (wn == half) {
#pragma unroll
        for (int j = 0; j < 4; j++) {
          int n = n0 + wn * 64 + j * 16 + col;
          float bv = f ? bf2f(((const unsigned short*)bias)[n]) : ((const float*)bias)[n];
          int dloc = j * 16 + col;
#pragma unroll
          for (int i = 0; i < 4; i++)
#pragma unroll
            for (int r = 0; r < 4; r++)
              Tr[dloc * 130 + wm * 64 + i * 16 + quad * 4 + r] = f2bf(acc[i][j][r] + bv);
        }
      }
      __syncthreads();
      const int r2 = t >> 2, seg = (t & 3) * 32;
      size_t gaddr = (((size_t)(bb * 16 + hh)) * 128 + half * 64 + r2) * 2048 + s0k + seg;
#pragma unroll
      for (int c = 0; c < 4; c++)
        *(bf16x8*)&Vt[gaddr + c * 8] = *(const bf16x8*)&Tr[r2 * 130 + seg + c * 8];
    }
    return;
  }

  const int f32o = final_out ? (f == 0) : 0;
#pragma unroll
  for (int j = 0; j < 4; j++) {
    int n = n0 + wn * 64 + j * 16 + col;
    float bv = f ? bf2f(((const unsigned short*)bias)[n]) : ((const float*)bias)[n];
#pragma unroll
    for (int i = 0; i < 4; i++)
#pragma unroll
      for (int r = 0; r < 4; r++) {
        int m = m0 + wm * 64 + i * 16 + quad * 4 + r;
        float v = acc[i][j][r] + bv;
        if (f32o) ((float*)Cout)[(size_t)m * N + n] = v;
        else      ((unsigned short*)Cout)[(size_t)m * N + n] = f2bf(v);
      }
  }
#undef As
#undef Bs
}

// ---------- flash attention (causal), paired q-tiles — round-6 winner ----------
// Block x in [0,16) processes qt = 31-x then qt = x  -> 33 iterations per block.
#define ATT_SCALE_L2E 0.12751743f  // (1/sqrt(128)) * log2(e)
__global__ __launch_bounds__(256) void attn_k(const unsigned short* __restrict__ qkv,
                                              const unsigned short* __restrict__ Vt,
                                              unsigned short* __restrict__ O) {
  __shared__ __attribute__((aligned(16))) unsigned short Ks[64][136];  // [key][d]
  __shared__ __attribute__((aligned(16))) unsigned short Vs[128][72];  // V^T: [d][key]
  __shared__ __attribute__((aligned(16))) unsigned short Ps[4][16][72];
  const int t = threadIdx.x;
  const int wave = t >> 6, lane = t & 63;
  const int col = lane & 15, quad = lane >> 4;
  const int h = blockIdx.y, b = blockIdx.z;
  const size_t base = (size_t)b * 2048 * 6144;
  const size_t vbase = ((size_t)(b * 16 + h)) * 128 * 2048;
  const int hcol = h * 128;

  const int kr = t >> 2;        // K staging: row 0..63
  const int kc = (t & 3) * 8;   // 0/8/16/24
  const int vr = t >> 1;        // V staging: d-row 0..127
  const int vc = (t & 1) * 32;  // 0/32

  const f32x4 fzero = {0.f, 0.f, 0.f, 0.f};

  for (int pass = 0; pass < 2; pass++) {
    const int qt = pass ? (int)blockIdx.x : 31 - (int)blockIdx.x;

    bf16x8 qf[4];  // Q A-fragments
    {
      size_t qrow = base + (size_t)(qt * 64 + wave * 16 + col) * 6144 + hcol;
#pragma unroll
      for (int ks = 0; ks < 4; ks++)
        qf[ks] = *(const bf16x8*)&qkv[qrow + ks * 32 + quad * 8];
    }

    f32x4 o[8];
#pragma unroll
    for (int i = 0; i < 8; i++) o[i] = fzero;
    float l_i[4] = {0.f, 0.f, 0.f, 0.f};

    __syncthreads();  // guard LDS vs previous pass readers
    {
      size_t grow = base + (size_t)kr * 6144 + 2048 + hcol;
#pragma unroll
      for (int p = 0; p < 4; p++)
        *(bf16x8*)&Ks[kr][kc + p * 32] = *(const bf16x8*)&qkv[grow + kc + p * 32];
      size_t vrow = vbase + (size_t)vr * 2048;
#pragma unroll
      for (int c = 0; c < 4; c++)
        *(bf16x8*)&Vs[vr][vc + c * 8] = *(const bf16x8*)&Vt[vrow + vc + c * 8];
    }
    __syncthreads();

    for (int kt = 0; kt <= qt; kt++) {
      bf16x8 kreg[4], vreg[4];
      const bool pf = (kt < qt);
      if (pf) {
        size_t grow = base + (size_t)((kt + 1) * 64 + kr) * 6144 + 2048 + hcol;
#pragma unroll
        for (int p = 0; p < 4; p++)
          kreg[p] = *(const bf16x8*)&qkv[grow + kc + p * 32];
        size_t vrow = vbase + (size_t)vr * 2048 + (kt + 1) * 64;
#pragma unroll
        for (int c = 0; c < 4; c++)
          vreg[c] = *(const bf16x8*)&Vt[vrow + vc + c * 8];
      }

      // S = Q @ K^T
      f32x4 sc[4];
#pragma unroll
      for (int nb = 0; nb < 4; nb++) {
        f32x4 s = fzero;
#pragma unroll
        for (int ks = 0; ks < 4; ks++) {
          bf16x8 kf = *(const bf16x8*)&Ks[nb * 16 + col][ks * 32 + quad * 8];
          s = __builtin_amdgcn_mfma_f32_16x16x32_bf16(qf[ks], kf, s, 0, 0, 0);
        }
        sc[nb] = s;
      }

      const bool diag = (kt == qt);
#pragma unroll
      for (int nb = 0; nb < 4; nb++) {
        int kl = nb * 16 + col;
#pragma unroll
        for (int r = 0; r < 4; r++) {
          float s = sc[nb][r];
          if (diag && kl > wave * 16 + quad * 4 + r) s = -1e30f;
          float p = exp2f(s * ATT_SCALE_L2E);
          l_i[r] += p;
          Ps[wave][quad * 4 + r][nb * 16 + col] = f2bf(p);
        }
      }
      bf16x8 pfr[2];
#pragma unroll
      for (int ks2 = 0; ks2 < 2; ks2++)
        pfr[ks2] = *(const bf16x8*)&Ps[wave][col][ks2 * 32 + quad * 8];
#pragma unroll
      for (int nbo = 0; nbo < 8; nbo++)
#pragma unroll
        for (int ks2 = 0; ks2 < 2; ks2++) {
          bf16x8 vf = *(const bf16x8*)&Vs[nbo * 16 + col][ks2 * 32 + quad * 8];
          o[nbo] = __builtin_amdgcn_mfma_f32_16x16x32_bf16(pfr[ks2], vf, o[nbo], 0, 0, 0);
        }

      __syncthreads();
      if (pf) {
#pragma unroll
        for (int p = 0; p < 4; p++)
          *(bf16x8*)&Ks[kr][kc + p * 32] = kreg[p];
#pragma unroll
        for (int c = 0; c < 4; c++)
          *(bf16x8*)&Vs[vr][vc + c * 8] = vreg[c];
      }
      __syncthreads();
    }

#pragma unroll
    for (int r = 0; r < 4; r++) {
#pragma unroll
      for (int off = 1; off < 16; off <<= 1)
        l_i[r] += __shfl_xor(l_i[r], off, 64);
      l_i[r] = 1.0f / l_i[r];
    }

#pragma unroll
    for (int nbo = 0; nbo < 8; nbo++)
#pragma unroll
      for (int r = 0; r < 4; r++) {
        int m = qt * 64 + wave * 16 + quad * 4 + r;
        O[((size_t)b * 2048 + m) * 2048 + hcol + nbo * 16 + col] = f2bf(o[nbo][r] * l_i[r]);
      }
  }
}

// ---------- launch ----------
extern "C" void kernel_launch(void* const* d_in, const int* in_sizes, int n_in,
                              void* d_out, int out_size, void* d_ws, size_t ws_size,
                              hipStream_t stream) {
  (void)in_sizes; (void)n_in; (void)out_size; (void)ws_size;
  int* flag = (int*)d_ws;
  unsigned short* wsu = (unsigned short*)d_ws + 128;
  unsigned short* Wt_qkv    = wsu;                                  // 6144*2048
  unsigned short* Wt_proj   = Wt_qkv + (size_t)6144 * 2048;         // 2048*2048
  unsigned short* QKV       = Wt_proj + (size_t)2048 * 2048;        // 4096*6144
  unsigned short* hidden_bf = QKV + (size_t)4096 * 6144;            // 4096*2048
  unsigned short* Vt        = hidden_bf + (size_t)4096 * 2048;      // 32*128*2048
  unsigned short* Obuf      = Wt_qkv;     // alias: dead after QKV gemm

  prologue_k<<<18432, 256, 0, stream>>>(d_in[0], d_in[1], d_in[3],
                                        hidden_bf, Wt_qkv, Wt_proj, flag);
  gemm_bias_k<<<dim3(48, 32), 256, 0, stream>>>((const unsigned short*)d_in[0], hidden_bf,
                                                Wt_qkv, d_in[2], QKV, Vt,
                                                4096, 6144, 2048, flag, 0, 1);
  attn_k<<<dim3(16, 16, 2), 256, 0, stream>>>(QKV, Vt, Obuf);
  gemm_bias_k<<<dim3(16, 32), 256, 0, stream>>>(Obuf, Obuf, Wt_proj, d_in[4], d_out, Vt,
                                                4096, 2048, 2048, flag, 1, 0);
}

// Round 10
// 429.532 us; speedup vs baseline: 1.0233x; 1.0233x over previous
//
#include <hip/hip_runtime.h>
#include <hip/hip_bf16.h>

// ---------- types & helpers ----------
typedef __bf16 bf16x8 __attribute__((ext_vector_type(8)));
typedef float f32x4 __attribute__((ext_vector_type(4)));

__device__ __forceinline__ float bf2f(unsigned short u) {
  union { unsigned int i; float f; } v; v.i = ((unsigned int)u) << 16; return v.f;
}
__device__ __forceinline__ unsigned short f2bf(float f) {
  union { unsigned int i; float f; } v; v.f = f;
  unsigned int i = v.i;
  return (unsigned short)((i + 0x7FFFu + ((i >> 16) & 1u)) >> 16);  // RNE
}

// async global->LDS, 16B per lane; LDS dest = wave-uniform base + lane*16
typedef const __attribute__((address_space(1))) unsigned int* gas_ptr;
typedef __attribute__((address_space(3))) unsigned int* las_ptr;
__device__ __forceinline__ void gload_lds16(const unsigned short* g, unsigned short* l) {
  __builtin_amdgcn_global_load_lds((gas_ptr)(const void*)g, (las_ptr)(void*)l, 16, 0, 0);
}

// ---------- fused prologue: detect + hidden cvt + both weight transposes ----------
__global__ __launch_bounds__(256) void prologue_k(const void* __restrict__ hidden,
                                                  const void* __restrict__ w_qkv,
                                                  const void* __restrict__ w_proj,
                                                  unsigned short* __restrict__ hidden_bf,
                                                  unsigned short* __restrict__ Wt_qkv,
                                                  unsigned short* __restrict__ Wt_proj,
                                                  int* __restrict__ flag) {
  __shared__ unsigned short tile[32][33];
  __shared__ int s4[4];
  const int t = threadIdx.x;
  {  // local dtype detect: 2048 even-indexed shorts of hidden (L2-broadcast)
    const unsigned short* h = (const unsigned short*)hidden;
    int cnt = 0;
    for (int i = t; i < 2048; i += 256) {
      unsigned short u = h[2 * i];
      int e = (u >> 7) & 0xFF;
      cnt += ((e >= 96 && e <= 140) || u == 0) ? 1 : 0;
    }
#pragma unroll
    for (int off = 1; off < 64; off <<= 1) cnt += __shfl_xor(cnt, off, 64);
    if ((t & 63) == 0) s4[t >> 6] = cnt;
  }
  __syncthreads();
  const int f = (s4[0] + s4[1] + s4[2] + s4[3]) >= 1800;  // bf16 ~2048; fp32 ~370
  if (blockIdx.x == 0 && t == 0) *flag = f;

  int bid = blockIdx.x;
  if (bid < 2048) {                 // hidden cvt (fp32 path only)
    if (f) return;
    const float* src = (const float*)hidden;
    int base = bid * 4096;
#pragma unroll
    for (int k = 0; k < 16; k++) hidden_bf[base + t + 256 * k] = f2bf(src[base + t + 256 * k]);
    return;
  }
  const void* src; unsigned short* dst; int C, cx, cy;
  if (bid < 14336) { bid -= 2048;  src = w_qkv;  dst = Wt_qkv;  C = 6144; cx = bid % 192; cy = bid / 192; }
  else             { bid -= 14336; src = w_proj; dst = Wt_proj; C = 2048; cx = bid % 64;  cy = bid / 64;  }
  const int x = t & 31, y = t >> 5;
  const int r0 = cy * 32, c0 = cx * 32;
#pragma unroll
  for (int i = 0; i < 4; i++) {
    size_t idx = (size_t)(r0 + y + 8 * i) * C + c0 + x;
    tile[y + 8 * i][x] = f ? ((const unsigned short*)src)[idx]
                           : f2bf(((const float*)src)[idx]);
  }
  __syncthreads();
#pragma unroll
  for (int i = 0; i < 4; i++)
    dst[(size_t)(c0 + y + 8 * i) * 2048 + r0 + x] = tile[x][y + 8 * i];
}

// ---------- V pre-transpose: Vt[(b*16+h)*128+d][key] ----------
__global__ __launch_bounds__(256) void transpose_v_k(const unsigned short* __restrict__ qkv,
                                                     unsigned short* __restrict__ Vt) {
  __shared__ unsigned short tile[32][33];
  const int bh = blockIdx.z;              // b*16+h
  const int b = bh >> 4, hh = bh & 15;
  const int s0 = blockIdx.x * 32, d0 = blockIdx.y * 32;
  const int x = threadIdx.x & 31, y = threadIdx.x >> 5;
#pragma unroll
  for (int i = 0; i < 4; i++)
    tile[y + 8 * i][x] =
        qkv[((size_t)b * 2048 + s0 + y + 8 * i) * 6144 + 4096 + hh * 128 + d0 + x];
  __syncthreads();
#pragma unroll
  for (int i = 0; i < 4; i++)
    Vt[((size_t)bh * 128 + d0 + y + 8 * i) * 2048 + s0 + x] = tile[x][y + 8 * i];
}

// ---------- GEMM 128x128 tile: global_load_lds + XOR-swizzled LDS ----------
// Round-6/8 winner: 854 TF, VGPR 80, zero conflicts. DO NOT add epilogue work:
// occupancy-fragile (round-9 v_fuse cost 22 us via VGPR 80->88).
__global__ __launch_bounds__(256) void gemm_bias_k(const unsigned short* __restrict__ A_bf,
                                                   const unsigned short* __restrict__ A_cvt,
                                                   const unsigned short* __restrict__ Bt,
                                                   const void* __restrict__ bias,
                                                   void* __restrict__ Cout,
                                                   int M, int N, int K,
                                                   const int* __restrict__ flag,
                                                   int final_out) {
  __shared__ __attribute__((aligned(16))) unsigned short As[128][64];
  __shared__ __attribute__((aligned(16))) unsigned short Bs[128][64];
  const int f = *flag;
  const unsigned short* A = f ? A_bf : A_cvt;
  const int t = threadIdx.x;
  const int wave = t >> 6, lane = t & 63;
  const int col = lane & 15, quad = lane >> 4;
  const int wm = wave >> 1, wn = wave & 1;
  const int m0 = blockIdx.y * 128, n0 = blockIdx.x * 128;
  const int srow = lane >> 3;
  const int schunk = ((lane & 7) ^ srow) * 8;       // swizzled source chunk
  const int rsw = col & 7;                          // read-side swizzle key

  const f32x4 fzero = {0.f, 0.f, 0.f, 0.f};
  f32x4 acc[4][4];
#pragma unroll
  for (int i = 0; i < 4; i++)
#pragma unroll
    for (int j = 0; j < 4; j++) acc[i][j] = fzero;

  for (int k0 = 0; k0 < K; k0 += 64) {
    __syncthreads();
#pragma unroll
    for (int c = 0; c < 4; c++) {
      int seg = wave * 4 + c;
      int row = seg * 8 + srow;
      gload_lds16(&A [(size_t)(m0 + row) * K + k0 + schunk], &As[seg * 8][0]);
      gload_lds16(&Bt[(size_t)(n0 + row) * K + k0 + schunk], &Bs[seg * 8][0]);
    }
    __syncthreads();
#pragma unroll
    for (int ks = 0; ks < 2; ks++) {
      bf16x8 af[4], bfr[4];
#pragma unroll
      for (int i = 0; i < 4; i++)
        af[i] = *(const bf16x8*)&As[wm * 64 + i * 16 + col][(((ks << 2) | quad) ^ rsw) * 8];
#pragma unroll
      for (int j = 0; j < 4; j++)
        bfr[j] = *(const bf16x8*)&Bs[wn * 64 + j * 16 + col][(((ks << 2) | quad) ^ rsw) * 8];
#pragma unroll
      for (int i = 0; i < 4; i++)
#pragma unroll
        for (int j = 0; j < 4; j++)
          acc[i][j] = __builtin_amdgcn_mfma_f32_16x16x32_bf16(af[i], bfr[j], acc[i][j], 0, 0, 0);
    }
  }
  const int f32o = final_out ? (f == 0) : 0;
#pragma unroll
  for (int j = 0; j < 4; j++) {
    int n = n0 + wn * 64 + j * 16 + col;
    float bv = f ? bf2f(((const unsigned short*)bias)[n]) : ((const float*)bias)[n];
#pragma unroll
    for (int i = 0; i < 4; i++)
#pragma unroll
      for (int r = 0; r < 4; r++) {
        int m = m0 + wm * 64 + i * 16 + quad * 4 + r;
        float v = acc[i][j][r] + bv;
        if (f32o) ((float*)Cout)[(size_t)m * N + n] = v;
        else      ((unsigned short*)Cout)[(size_t)m * N + n] = f2bf(v);
      }
  }
}

// ---------- flash attention (causal): DMA double-buffered K/V, 1 barrier/iter ----------
// Block x in [0,16): qt = 31-x then qt = x (33 iters each, balanced).
// K/V staged by global_load_lds into alternating unpadded buffers with the
// gemm's XOR chunk swizzle (reads at chunk^(row&7): 2-way banks = free).
// The iter-end __syncthreads' vmcnt drain doubles as DMA completion.
#define ATT_SCALE_L2E 0.12751743f  // (1/sqrt(128)) * log2(e)
__global__ __launch_bounds__(256) void attn_k(const unsigned short* __restrict__ qkv,
                                              const unsigned short* __restrict__ Vt,
                                              unsigned short* __restrict__ O) {
  __shared__ __attribute__((aligned(16))) unsigned short Ks[2][64][128];  // [key][d]
  __shared__ __attribute__((aligned(16))) unsigned short Vs[2][128][64];  // [d][key]
  __shared__ __attribute__((aligned(16))) unsigned short Ps[4][16][72];
  const int t = threadIdx.x;
  const int wave = t >> 6, lane = t & 63;
  const int col = lane & 15, quad = lane >> 4;
  const int h = blockIdx.y, b = blockIdx.z;
  const size_t base = (size_t)b * 2048 * 6144;
  const size_t vbase = ((size_t)(b * 16 + h)) * 128 * 2048;
  const int hcol = h * 128;

  // K DMA: inst i covers key rows 4i..4i+3; lane -> row 4i+(lane>>4), chunk lane&15
  const int k_rl = lane >> 4;                       // 0..3
  const int k_ch = lane & 15;
  // V DMA: inst j covers d rows 8j..8j+7; lane -> d 8j+(lane>>3), chunk lane&7
  const int v_dl = lane >> 3;                       // 0..7
  const int v_ch = ((lane & 7) ^ (v_dl & 7)) * 8;   // swizzled source chunk (shorts)
  const int rsw = col & 7;                          // read-side swizzle key

  const f32x4 fzero = {0.f, 0.f, 0.f, 0.f};

  for (int pass = 0; pass < 2; pass++) {
    const int qt = pass ? (int)blockIdx.x : 31 - (int)blockIdx.x;

    bf16x8 qf[4];  // Q A-fragments (m=lane&15, k=quad*8+j)
    {
      size_t qrow = base + (size_t)(qt * 64 + wave * 16 + col) * 6144 + hcol;
#pragma unroll
      for (int ks = 0; ks < 4; ks++)
        qf[ks] = *(const bf16x8*)&qkv[qrow + ks * 32 + quad * 8];
    }

    f32x4 o[8];
#pragma unroll
    for (int i = 0; i < 8; i++) o[i] = fzero;
    float l_i[4] = {0.f, 0.f, 0.f, 0.f};

    __syncthreads();  // prior pass readers done
    // stage tile kt=0 into buf 0 (DMA)
#pragma unroll
    for (int c = 0; c < 4; c++) {
      int i = wave * 4 + c;  // 16 K-insts
      int row = 4 * i + k_rl;
      int sch = (k_ch ^ (row & 7)) * 8;
      gload_lds16(&qkv[base + (size_t)row * 6144 + 2048 + hcol + sch], &Ks[0][4 * i][0]);
      int d = 8 * i + v_dl;  // 16 V-insts
      gload_lds16(&Vt[vbase + (size_t)d * 2048 + v_ch], &Vs[0][8 * i][0]);
    }
    __syncthreads();  // drains vmcnt -> tile 0 ready

    for (int kt = 0; kt <= qt; kt++) {
      const int buf = kt & 1;
      // issue DMA of tile kt+1 into the other buffer (no one reads it this iter)
      if (kt < qt) {
        const int nb1 = buf ^ 1;
#pragma unroll
        for (int c = 0; c < 4; c++) {
          int i = wave * 4 + c;
          int row = 4 * i + k_rl;
          int sch = (k_ch ^ (row & 7)) * 8;
          gload_lds16(&qkv[base + (size_t)((kt + 1) * 64 + row) * 6144 + 2048 + hcol + sch],
                      &Ks[nb1][4 * i][0]);
          int d = 8 * i + v_dl;
          gload_lds16(&Vt[vbase + (size_t)d * 2048 + (kt + 1) * 64 + v_ch], &Vs[nb1][8 * i][0]);
        }
      }

      // S = Q @ K^T
      f32x4 sc[4];
#pragma unroll
      for (int nb = 0; nb < 4; nb++) {
        f32x4 s = fzero;
#pragma unroll
        for (int ks = 0; ks < 4; ks++) {
          bf16x8 kf = *(const bf16x8*)&Ks[buf][nb * 16 + col][(((ks << 2) | quad) ^ rsw) * 8];
          s = __builtin_amdgcn_mfma_f32_16x16x32_bf16(qf[ks], kf, s, 0, 0, 0);
        }
        sc[nb] = s;
      }

      const bool diag = (kt == qt);
#pragma unroll
      for (int nb = 0; nb < 4; nb++) {
        int kl = nb * 16 + col;
#pragma unroll
        for (int r = 0; r < 4; r++) {
          float s = sc[nb][r];
          if (diag && kl > wave * 16 + quad * 4 + r) s = -1e30f;
          float p = exp2f(s * ATT_SCALE_L2E);
          l_i[r] += p;
          Ps[wave][quad * 4 + r][nb * 16 + col] = f2bf(p);
        }
      }
      bf16x8 pfr[2];  // per-wave LDS roundtrip, no barrier
#pragma unroll
      for (int ks2 = 0; ks2 < 2; ks2++)
        pfr[ks2] = *(const bf16x8*)&Ps[wave][col][ks2 * 32 + quad * 8];
#pragma unroll
      for (int nbo = 0; nbo < 8; nbo++) {
        const int d = nbo * 16 + col;
#pragma unroll
        for (int ks2 = 0; ks2 < 2; ks2++) {
          bf16x8 vf = *(const bf16x8*)&Vs[buf][d][(((ks2 << 2) | quad) ^ rsw) * 8];
          o[nbo] = __builtin_amdgcn_mfma_f32_16x16x32_bf16(pfr[ks2], vf, o[nbo], 0, 0, 0);
        }
      }

      __syncthreads();  // waves done with buf; vmcnt drain completes tile kt+1
    }

#pragma unroll
    for (int r = 0; r < 4; r++) {
#pragma unroll
      for (int off = 1; off < 16; off <<= 1)
        l_i[r] += __shfl_xor(l_i[r], off, 64);
      l_i[r] = 1.0f / l_i[r];
    }

#pragma unroll
    for (int nbo = 0; nbo < 8; nbo++)
#pragma unroll
      for (int r = 0; r < 4; r++) {
        int m = qt * 64 + wave * 16 + quad * 4 + r;
        O[((size_t)b * 2048 + m) * 2048 + hcol + nbo * 16 + col] = f2bf(o[nbo][r] * l_i[r]);
      }
  }
}

// ---------- launch ----------
extern "C" void kernel_launch(void* const* d_in, const int* in_sizes, int n_in,
                              void* d_out, int out_size, void* d_ws, size_t ws_size,
                              hipStream_t stream) {
  (void)in_sizes; (void)n_in; (void)out_size; (void)ws_size;
  int* flag = (int*)d_ws;
  unsigned short* wsu = (unsigned short*)d_ws + 128;
  unsigned short* Wt_qkv    = wsu;                                  // 6144*2048
  unsigned short* Wt_proj   = Wt_qkv + (size_t)6144 * 2048;         // 2048*2048
  unsigned short* QKV       = Wt_proj + (size_t)2048 * 2048;        // 4096*6144
  unsigned short* hidden_bf = QKV + (size_t)4096 * 6144;            // 4096*2048
  unsigned short* Vt        = Wt_qkv;     // alias: Wt_qkv dead after gemm1
  unsigned short* Obuf      = hidden_bf;  // alias: hidden_bf dead after gemm1

  prologue_k<<<18432, 256, 0, stream>>>(d_in[0], d_in[1], d_in[3],
                                        hidden_bf, Wt_qkv, Wt_proj, flag);
  gemm_bias_k<<<dim3(48, 32), 256, 0, stream>>>((const unsigned short*)d_in[0], hidden_bf,
                                                Wt_qkv, d_in[2], QKV,
                                                4096, 6144, 2048, flag, 0);
  transpose_v_k<<<dim3(64, 4, 32), 256, 0, stream>>>(QKV, Vt);
  attn_k<<<dim3(16, 16, 2), 256, 0, stream>>>(QKV, Vt, Obuf);
  gemm_bias_k<<<dim3(16, 32), 256, 0, stream>>>(Obuf, Obuf, Wt_proj, d_in[4], d_out,
                                                4096, 2048, 2048, flag, 1);
}